// Round 20
// baseline (257.182 us; speedup 1.0000x reference)
//
#include <hip/hip_runtime.h>
#include <math.h>

typedef __bf16 bf16_t;
typedef __bf16 bf16x4 __attribute__((ext_vector_type(4)));
typedef __bf16 bf16x8 __attribute__((ext_vector_type(8)));
typedef float  f32x4  __attribute__((ext_vector_type(4)));

#define FNUM 256
#define KPAD 608            // 600 padded to 608 (19 K-steps of 32)
#define NKS  19

// ---------------- W prep: f32 [256][600] -> swizzled bf16 MFMA-fragment tiles ----------------
// Tile (ks, ft): 64 lanes x 8 bf16 contiguous. lane l -> f = ft*16+(l&15), k = ks*32+(l>>4)*8+e.
__global__ __launch_bounds__(256)
void prep_w_swz(const float* __restrict__ w0, const float* __restrict__ w1,
                const float* __restrict__ w2, const float* __restrict__ w3,
                const float* __restrict__ w4, bf16_t* __restrict__ wp) {
    int tg = blockIdx.x * 4 + (threadIdx.x >> 6);    // 5*19*16 = 1520 tiles
    if (tg >= 1520) return;
    int l  = threadIdx.x & 63;
    int br = tg / 304;
    int rem = tg % 304;
    int ks = rem / 16, ft = rem % 16;
    const float* src;
    switch (br) {
        case 0: src = w0; break;
        case 1: src = w1; break;
        case 2: src = w2; break;
        case 3: src = w3; break;
        default: src = w4; break;
    }
    int f = ft * 16 + (l & 15);
    int k0 = ks * 32 + (l >> 4) * 8;
    bf16x8 v;
#pragma unroll
    for (int e = 0; e < 8; e++) {
        int k = k0 + e;
        v[e] = (k < 600) ? (bf16_t)src[(size_t)f * 600 + k] : (bf16_t)0.f;
    }
    *(bf16x8*)(wp + (size_t)br * FNUM * KPAD + ((size_t)(ks * 16 + ft) * 512 + (size_t)l * 8)) = v;
}

// ---------------- body conv tile: ONE 256f x 64t chunk per block, 256 thr, 4 blocks/CU ----------------
// 4 waves; wave w owns f [w*64, w*64+64) (4 m-frags) x ALL 64 t (4 n-frags) -> acc[4][4],
// 16 MFMA/step/wave (R15-proven ILP), 4 W-tile loads/step (16 distinct per block -> no dup).
// Same 16 waves/CU as R15/R19 but 4 finer blocks: while one block runs its serial stage,
// the other 3 compute -> cross-block stage/compute overlap. feat aliased into Xlds
// (barrier after K-loop) keeps LDS at 39.0 KB -> 4 blocks/CU.
// __launch_bounds__(256, 4): unified reg usage ~126 must land <=128 for 4 waves/SIMD.
// grid = 4100: bid < 4096 -> batch = bid>>2, chunk c = bid&3; bid >= 4096 -> doc chunk.
// Partial t-sums -> part[(batch*4 + c)*256 + f] (doc slots 4096..4099).
__global__ __launch_bounds__(256, 4)
void conv_body(const float* __restrict__ X, const bf16_t* __restrict__ Wswz,
               const float* __restrict__ bias, float* __restrict__ part,
               const float* __restrict__ X2, const bf16_t* __restrict__ W2,
               const float* __restrict__ bias2) {
    constexpr int NFRAG = 4;
    constexpr int TT    = 64;
    constexpr int NROWS = TT + 1;
    __shared__ bf16_t Xlds[NROWS * 300 + 8];     // 39,016 B; aliased as feat after K-loop

    const int tid = threadIdx.x;
    const int l   = tid & 63;
    const int w   = tid >> 6;        // wave 0..3
    const int g   = l >> 4;
    const int l15 = l & 15;

    const float* Xb;
    const bf16_t* Wb;
    const float* bp;
    int slot, t0;
    if ((int)blockIdx.x >= 4096) {               // doc rider
        int c = blockIdx.x - 4096;
        Xb = X2; Wb = W2; bp = bias2;
        slot = 4096 + c;
        t0 = c * TT;
    } else {
        int batch = blockIdx.x >> 2;
        int c = blockIdx.x & 3;
        Xb = X + (size_t)batch * 60000;
        Wb = Wswz; bp = bias;
        slot = batch * 4 + c;
        t0 = c * TT;
    }

    // ---- stage rows [t0, t0+NROWS) of X as bf16, 4 loads in flight per thread ----
    {
        const int vr  = (200 - t0 < NROWS) ? (200 - t0) : NROWS;
        const float4* s4 = (const float4*)(Xb + (size_t)t0 * 300);
        const int nF4 = vr * 75;
        for (int v0 = tid; v0 < nF4; v0 += 256 * 4) {
            float4 t[4];
#pragma unroll
            for (int q = 0; q < 4; ++q) {
                int v = v0 + q * 256;
                if (v < nF4) t[q] = s4[v];
            }
#pragma unroll
            for (int q = 0; q < 4; ++q) {
                int v = v0 + q * 256;
                if (v < nF4) {
                    bf16x4 hv = { (bf16_t)t[q].x, (bf16_t)t[q].y, (bf16_t)t[q].z, (bf16_t)t[q].w };
                    *(bf16x4*)(Xlds + v * 4) = hv;
                }
            }
        }
        bf16x4 z4 = { (bf16_t)0.f, (bf16_t)0.f, (bf16_t)0.f, (bf16_t)0.f };
        for (int v = nF4 + tid; v < NROWS * 75; v += 256)
            *(bf16x4*)(Xlds + v * 4) = z4;
        if (tid < 4) ((unsigned int*)(Xlds + NROWS * 300))[tid] = 0u;   // 16B guard (k->607 overrun)
    }

    // A-tile pointer: wave w's 4 f-tiles at K-step ks live at ((ks*16 + w*4 + i)*512 + l*8)
    const bf16_t* wa = Wb + ((size_t)(w * 4) * 512 + (size_t)l * 8);

    int boff[NFRAG];
#pragma unroll
    for (int j = 0; j < NFRAG; j++)
        boff[j] = (j * 16 + l15) * 300 + g * 8;

    bf16x8 aCur[4], aNxt[4];
#pragma unroll
    for (int i = 0; i < 4; i++) aCur[i] = *(const bf16x8*)(wa + i * 512);

    __syncthreads();

    f32x4 acc[4][NFRAG];
#pragma unroll
    for (int i = 0; i < 4; i++)
#pragma unroll
        for (int j = 0; j < NFRAG; j++)
            acc[i][j] = (f32x4){0.f, 0.f, 0.f, 0.f};

    for (int ks = 0; ks < NKS; ++ks) {
        if (ks + 1 < NKS) {
            const bf16_t* wn_p = wa + (size_t)(ks + 1) * 16 * 512;
#pragma unroll
            for (int i = 0; i < 4; i++) aNxt[i] = *(const bf16x8*)(wn_p + i * 512);
        }
        const int k0 = ks * 32;
        bf16x8 bb[NFRAG];
#pragma unroll
        for (int j = 0; j < NFRAG; j++) {
            bf16x4 lo = *(const bf16x4*)(Xlds + boff[j] + k0);
            bf16x4 hi = *(const bf16x4*)(Xlds + boff[j] + k0 + 4);
            bb[j] = __builtin_shufflevector(lo, hi, 0, 1, 2, 3, 4, 5, 6, 7);
        }
#pragma unroll
        for (int i = 0; i < 4; i++)
#pragma unroll
            for (int j = 0; j < NFRAG; j++)
                acc[i][j] = __builtin_amdgcn_mfma_f32_16x16x32_bf16(aCur[i], bb[j], acc[i][j], 0, 0, 0);
#pragma unroll
        for (int i = 0; i < 4; i++) aCur[i] = aNxt[i];
    }

    __syncthreads();   // all waves done reading Xlds -> safe to alias as feat buffer
    float* feat = (float*)Xlds;   // 256 floats

    // ---- epilogue: relu(C + bias), mask t<199, reduce over t; coalesced write via feat ----
#pragma unroll
    for (int i = 0; i < 4; i++) {
#pragma unroll
        for (int r = 0; r < 4; r++) {
            const int row = w * 64 + i * 16 + g * 4 + r;
            const float bi = bp[row];
            float s = 0.f;
#pragma unroll
            for (int j = 0; j < NFRAG; j++) {
                int t = t0 + j * 16 + l15;
                float v = acc[i][j][r] + bi;
                v = fmaxf(v, 0.f);
                s += (t < 199) ? v : 0.f;
            }
            s += __shfl_xor(s, 1);
            s += __shfl_xor(s, 2);
            s += __shfl_xor(s, 4);
            s += __shfl_xor(s, 8);
            if (l15 == 0) feat[row] = s;
        }
    }
    __syncthreads();
    part[(size_t)slot * 256 + tid] = feat[tid];
}

// ---------------- combine 4 partials + unit-normalize; nebT column-major, doc -> nmd ----------------
__global__ __launch_bounds__(256)
void combine_norm(const float* __restrict__ part, float* __restrict__ nebT,
                  float* __restrict__ nmd) {
    __shared__ float red[4];
    int bid = blockIdx.x, tid = threadIdx.x;
    float v = part[((size_t)bid * 4 + 0) * 256 + tid]
            + part[((size_t)bid * 4 + 1) * 256 + tid]
            + part[((size_t)bid * 4 + 2) * 256 + tid]
            + part[((size_t)bid * 4 + 3) * 256 + tid];
    float sq = v * v;
    sq += __shfl_xor(sq, 1);
    sq += __shfl_xor(sq, 2);
    sq += __shfl_xor(sq, 4);
    sq += __shfl_xor(sq, 8);
    sq += __shfl_xor(sq, 16);
    sq += __shfl_xor(sq, 32);
    if ((tid & 63) == 0) red[tid >> 6] = sq;
    __syncthreads();
    float tot = red[0] + red[1] + red[2] + red[3];
    float o = v / sqrtf(tot);
    if (bid >= 1024) nmd[tid] = o;
    else             nebT[(size_t)tid * 1024 + bid] = o;
}

// ---------------- small branches: 4 batches per block, all indices compile-time ----------------
template<int NF>
__device__ __forceinline__ void kloop_s(const bf16_t* __restrict__ wa,
        const bf16_t* __restrict__ buf, f32x4 (&acc)[2][NF], const int (&boff)[NF]) {
    bf16x8 aCur[2], aNxt[2];
    aCur[0] = *(const bf16x8*)(wa);
    aCur[1] = *(const bf16x8*)(wa + 512);
#pragma unroll
    for (int ks = 0; ks < NKS; ++ks) {
        if (ks + 1 < NKS) {
            const bf16_t* wn = wa + (size_t)(ks + 1) * (16 * 512);
            aNxt[0] = *(const bf16x8*)(wn);
            aNxt[1] = *(const bf16x8*)(wn + 512);
        }
        const int k0 = ks * 32;
#pragma unroll
        for (int j = 0; j < NF; ++j) {
            const bf16_t* p = buf + boff[j] + k0;
            bf16x4 lo = *(const bf16x4*)(p);
            bf16x4 hi = *(const bf16x4*)(p + 4);
            bf16x8 bb = __builtin_shufflevector(lo, hi, 0, 1, 2, 3, 4, 5, 6, 7);
            acc[0][j] = __builtin_amdgcn_mfma_f32_16x16x32_bf16(aCur[0], bb, acc[0][j], 0, 0, 0);
            acc[1][j] = __builtin_amdgcn_mfma_f32_16x16x32_bf16(aCur[1], bb, acc[1][j], 0, 0, 0);
        }
        aCur[0] = aNxt[0]; aCur[1] = aNxt[1];
    }
}

template<int NFB, int L, int T, int BSTR, int ARRE>
__global__ __launch_bounds__(512, 4)
void conv_small(const float* __restrict__ XA, const bf16_t* __restrict__ WA,
                const float* __restrict__ bA, float* __restrict__ outA,
                const float* __restrict__ XB, const bf16_t* __restrict__ WB,
                const float* __restrict__ bB, float* __restrict__ outB,
                int nABlocks) {
    constexpr int NTOT = 4 * NFB;
    __shared__ bf16_t Xs[ARRE];
    __shared__ float feat4[4][256];

    const int tid = threadIdx.x, l = tid & 63, w = tid >> 6, g = l >> 4, l15 = l & 15;
    const bool modeA = ((int)blockIdx.x < nABlocks);
    const int grp = modeA ? (int)blockIdx.x : ((int)blockIdx.x - nABlocks);
    const int batch0 = grp * 4;
    const float* Xsrc = modeA ? XA : XB;
    const bf16_t* Wb = modeA ? WA : WB;
    const float* bp = modeA ? bA : bB;

#pragma unroll
    for (int b = 0; b < 4; ++b) {
        const float4* s4 = (const float4*)(Xsrc + (size_t)(batch0 + b) * (L * 300));
        for (int v = tid; v < L * 75; v += 512) {
            float4 f = s4[v];
            bf16x4 h = { (bf16_t)f.x, (bf16_t)f.y, (bf16_t)f.z, (bf16_t)f.w };
            *(bf16x4*)(Xs + b * BSTR + v * 4) = h;
        }
        if (tid < 2) {
            bf16x4 z = { (bf16_t)0.f, (bf16_t)0.f, (bf16_t)0.f, (bf16_t)0.f };
            *(bf16x4*)(Xs + b * BSTR + L * 300 + tid * 4) = z;
        }
    }
    __syncthreads();

    int boff[NTOT];
#pragma unroll
    for (int j = 0; j < NTOT; ++j)
        boff[j] = (j / NFB) * BSTR + ((j % NFB) * 16 + l15) * 300 + g * 8;

    f32x4 acc[2][NTOT];
#pragma unroll
    for (int a = 0; a < 2; a++)
#pragma unroll
        for (int j = 0; j < NTOT; j++) acc[a][j] = (f32x4){0.f, 0.f, 0.f, 0.f};

    const bf16_t* wa = Wb + (size_t)(2 * w) * 512 + (size_t)l * 8;
    kloop_s<NTOT>(wa, Xs, acc, boff);

#pragma unroll
    for (int jb = 0; jb < 4; ++jb) {
#pragma unroll
        for (int a = 0; a < 2; a++)
#pragma unroll
            for (int r = 0; r < 4; r++) {
                const float bi = bp[32 * w + a * 16 + g * 4 + r];
                float s = 0.f;
#pragma unroll
                for (int jf = 0; jf < NFB; ++jf) {
                    int t = jf * 16 + l15;
                    float v = acc[a][jb * NFB + jf][r] + bi;
                    v = fmaxf(v, 0.f);
                    s += (t < T) ? v : 0.f;
                }
                s += __shfl_xor(s, 1);
                s += __shfl_xor(s, 2);
                s += __shfl_xor(s, 4);
                s += __shfl_xor(s, 8);
                if (l15 == 0) feat4[jb][32 * w + a * 16 + g * 4 + r] = s;
            }
    }
    __syncthreads();

    if (w < 4) {
        float vv[4];
        float sq = 0.f;
#pragma unroll
        for (int q = 0; q < 4; q++) { vv[q] = feat4[w][l * 4 + q]; sq += vv[q] * vv[q]; }
        sq += __shfl_xor(sq, 1);
        sq += __shfl_xor(sq, 2);
        sq += __shfl_xor(sq, 4);
        sq += __shfl_xor(sq, 8);
        sq += __shfl_xor(sq, 16);
        sq += __shfl_xor(sq, 32);
        float rsq = 1.f / sqrtf(sq);
        int batch = batch0 + w;
        if (modeA) {
#pragma unroll
            for (int q = 0; q < 4; q++)
                outA[(size_t)(l * 4 + q) * 1024 + batch] = vv[q] * rsq;
        } else {
            float4 o = { vv[0] * rsq, vv[1] * rsq, vv[2] * rsq, vv[3] * rsq };
            *(float4*)(outB + (size_t)batch * 256 + l * 4) = o;
        }
    }
}

// ---------------- pair pass 1: tile 4m x 256n per block (grid 256); dt/db FUSED inline ----------------
__global__ __launch_bounds__(256)
void pair1(const float* __restrict__ nms, const float* __restrict__ nmc,
           const float* __restrict__ netT, const float* __restrict__ nebT,
           const float* __restrict__ nmd,
           const float* __restrict__ wl, const float* __restrict__ bl,
           const int* __restrict__ me, float* __restrict__ out,
           float* __restrict__ epart) {
    __shared__ float sA[4 * 256], sB[4 * 256], md[256];
    const int tid = threadIdx.x;
    const int mt = blockIdx.x >> 2;
    const int nt = blockIdx.x & 3;
    const int m0 = mt * 4, n0 = nt * 256;
    for (int v = tid; v < 1024; v += 256) {
        sA[v] = nms[(size_t)m0 * 256 + v];
        sB[v] = nmc[(size_t)m0 * 256 + v];
    }
    md[tid] = nmd[tid];
    __syncthreads();
    const int ws = tid >> 6;
    const int nl = tid & 63;
    const int n  = n0 + nl * 4;
    const int m  = m0 + ws;

    float dst[4] = {0,0,0,0}, dct[4] = {0,0,0,0}, dsb[4] = {0,0,0,0}, dcb[4] = {0,0,0,0};
    float dtq[4] = {0,0,0,0}, dbq[4] = {0,0,0,0};
    for (int k = 0; k < 256; ++k) {
        float4 tv = *(const float4*)(netT + (size_t)k * 1024 + n);
        float4 bv = *(const float4*)(nebT + (size_t)k * 1024 + n);
        float a = sA[ws * 256 + k];
        float c = sB[ws * 256 + k];
        float mk = md[k];
        dst[0] += a * tv.x; dst[1] += a * tv.y; dst[2] += a * tv.z; dst[3] += a * tv.w;
        dct[0] += c * tv.x; dct[1] += c * tv.y; dct[2] += c * tv.z; dct[3] += c * tv.w;
        dsb[0] += a * bv.x; dsb[1] += a * bv.y; dsb[2] += a * bv.z; dsb[3] += a * bv.w;
        dcb[0] += c * bv.x; dcb[1] += c * bv.y; dcb[2] += c * bv.z; dcb[3] += c * bv.w;
        dtq[0] += mk * tv.x; dtq[1] += mk * tv.y; dtq[2] += mk * tv.z; dtq[3] += mk * tv.w;
        dbq[0] += mk * bv.x; dbq[1] += mk * bv.y; dbq[2] += mk * bv.z; dbq[3] += mk * bv.w;
    }

    float w0 = wl[0], w1 = wl[1], w2 = wl[2], w3 = wl[3], w4 = wl[4], w5 = wl[5], b = bl[0];
    const int* mp = me + (size_t)m * 1024 + n;
    float scv[4], evv[4];
    float esum = 0.f;
#pragma unroll
    for (int q = 0; q < 4; q++) {
        float msk = (float)mp[q];
        float f_st = dst[q] * 0.5f + 0.5f;
        float f_dt = dtq[q] * 0.5f + 0.5f;
        float f_ct = dct[q] * 0.5f + 0.5f;
        float f_sb = dsb[q] * 0.5f + 0.5f;
        float f_db = dbq[q] * 0.5f + 0.5f;
        float f_cb = dcb[q] * 0.5f + 0.5f;
        float s = f_st * w0 + f_dt * w1 + f_ct * w2 + f_sb * w3 + f_db * w4 + f_cb * w5 + b;
        s = (msk != 0.f) ? s : 0.f;
        scv[q] = s;
        evv[q] = (msk != 0.f) ? expf(s / 0.1f) : 0.f;
        esum += evv[q];
    }
    esum += __shfl_xor(esum, 1);
    esum += __shfl_xor(esum, 2);
    esum += __shfl_xor(esum, 4);
    esum += __shfl_xor(esum, 8);
    esum += __shfl_xor(esum, 16);
    esum += __shfl_xor(esum, 32);
    if (nl == 0) epart[(size_t)m * 4 + nt] = esum;

    *(float4*)(out + (size_t)m * 1024 + n) = *(float4*)scv;
    *(float4*)(out + 262144 + (size_t)m * 1024 + n) = *(float4*)evv;
}

// ---------------- pair pass 2: row-normalize e in place ----------------
__global__ __launch_bounds__(256)
void pair2(const float* __restrict__ epart, float* __restrict__ out2) {
    int m = blockIdx.x, tid = threadIdx.x;
    float tot = epart[(size_t)m * 4 + 0] + epart[(size_t)m * 4 + 1]
              + epart[(size_t)m * 4 + 2] + epart[(size_t)m * 4 + 3];
    float inv = 1.f / tot;
#pragma unroll
    for (int q = 0; q < 4; q++)
        out2[(size_t)m * 1024 + q * 256 + tid] *= inv;
}

extern "C" void kernel_launch(void* const* d_in, const int* in_sizes, int n_in,
                              void* d_out, int out_size, void* d_ws, size_t ws_size,
                              hipStream_t stream) {
    const float* mention = (const float*)d_in[0];
    const float* context = (const float*)d_in[1];
    const float* doc     = (const float*)d_in[2];
    const float* title   = (const float*)d_in[3];
    const float* body    = (const float*)d_in[4];
    const float* W_ms = (const float*)d_in[5];  const float* b_ms = (const float*)d_in[6];
    const float* W_mc = (const float*)d_in[7];  const float* b_mc = (const float*)d_in[8];
    const float* W_md = (const float*)d_in[9];  const float* b_md = (const float*)d_in[10];
    const float* W_et = (const float*)d_in[11]; const float* b_et = (const float*)d_in[12];
    const float* W_eb = (const float*)d_in[13]; const float* b_eb = (const float*)d_in[14];
    const float* w_local = (const float*)d_in[15];
    const float* b_local = (const float*)d_in[16];
    const int*   me      = (const int*)d_in[17];
    float* out = (float*)d_out;

    char* ws = (char*)d_ws;
    bf16_t* Wp = (bf16_t*)ws;
    size_t off = (size_t)5 * FNUM * KPAD * 2;             // swizzled W: 1,556,480 B
    float* part = (float*)(ws + off); off += (size_t)1025 * 4 * 256 * 4;
    float* nms  = (float*)(ws + off); off += 256 * 256 * 4;
    float* nmc  = (float*)(ws + off); off += 256 * 256 * 4;
    float* netT = (float*)(ws + off); off += 1024 * 256 * 4;
    float* nebT = (float*)(ws + off); off += 1024 * 256 * 4;
    float* nmd  = (float*)(ws + off); off += 256 * 4;
    float* epart= (float*)(ws + off); off += 256 * 4 * 4;

    const bf16_t* Wms = Wp + (size_t)0 * FNUM * KPAD;
    const bf16_t* Wmc = Wp + (size_t)1 * FNUM * KPAD;
    const bf16_t* Wmd = Wp + (size_t)2 * FNUM * KPAD;
    const bf16_t* Wet = Wp + (size_t)3 * FNUM * KPAD;
    const bf16_t* Web = Wp + (size_t)4 * FNUM * KPAD;

    prep_w_swz<<<380, 256, 0, stream>>>(W_ms, W_mc, W_md, W_et, W_eb, Wp);

    // body: 256-thread blocks, 4 chunks of 64t per batch + 4 doc chunks (grid 4100)
    conv_body<<<4100, 256, 0, stream>>>(body, Web, b_eb, part, doc, Wmd, b_md);

    conv_small<2, 20, 19, 6016, 27968><<<320, 512, 0, stream>>>(
        title, Wet, b_et, netT, context, Wmc, b_mc, nmc, 256);
    conv_small<1, 10, 9, 5120, 20480><<<64, 512, 0, stream>>>(
        mention, Wms, b_ms, netT, mention, Wms, b_ms, nms, 0);

    combine_norm<<<1025, 256, 0, stream>>>(part, nebT, nmd);
    pair1<<<256, 256, 0, stream>>>(nms, nmc, netT, nebT, nmd, w_local, b_local, me, out, epart);
    pair2<<<256, 256, 0, stream>>>(epart, out + 262144);
}

// Round 21
// 217.876 us; speedup vs baseline: 1.1804x; 1.1804x over previous
//
#include <hip/hip_runtime.h>
#include <math.h>

typedef __bf16 bf16_t;
typedef __bf16 bf16x4 __attribute__((ext_vector_type(4)));
typedef __bf16 bf16x8 __attribute__((ext_vector_type(8)));
typedef float  f32x4  __attribute__((ext_vector_type(4)));

#define FNUM 256
#define KPAD 608            // 600 padded to 608 (19 K-steps of 32)
#define NKS  19

// ---------------- W prep: f32 [256][600] -> swizzled bf16 MFMA-fragment tiles ----------------
// Tile (ks, ft): 64 lanes x 8 bf16 contiguous. lane l -> f = ft*16+(l&15), k = ks*32+(l>>4)*8+e.
__global__ __launch_bounds__(256)
void prep_w_swz(const float* __restrict__ w0, const float* __restrict__ w1,
                const float* __restrict__ w2, const float* __restrict__ w3,
                const float* __restrict__ w4, bf16_t* __restrict__ wp) {
    int tg = blockIdx.x * 4 + (threadIdx.x >> 6);    // 5*19*16 = 1520 tiles
    if (tg >= 1520) return;
    int l  = threadIdx.x & 63;
    int br = tg / 304;
    int rem = tg % 304;
    int ks = rem / 16, ft = rem % 16;
    const float* src;
    switch (br) {
        case 0: src = w0; break;
        case 1: src = w1; break;
        case 2: src = w2; break;
        case 3: src = w3; break;
        default: src = w4; break;
    }
    int f = ft * 16 + (l & 15);
    int k0 = ks * 32 + (l >> 4) * 8;
    bf16x8 v;
#pragma unroll
    for (int e = 0; e < 8; e++) {
        int k = k0 + e;
        v[e] = (k < 600) ? (bf16_t)src[(size_t)f * 600 + k] : (bf16_t)0.f;
    }
    *(bf16x8*)(wp + (size_t)br * FNUM * KPAD + ((size_t)(ks * 16 + ft) * 512 + (size_t)l * 8)) = v;
}

// ---------------- body conv tile: ONE 256f x 128t chunk per block, 8M x 1N waves ----------------
// 512 threads = 8 waves; wave w owns f [w*32, w*32+32) (2 m-frags) x ALL 128 t (8 n-frags)
// -> 16 MFMA/step/wave, 2 W-tile loads/step, no L1 duplication. Batched stage (4 float4 in
// flight). s_setprio(1) brackets the MFMA cluster: with 2 independent blocks/CU, MFMA waves
// of one block win issue arbitration over the other block's staging waves (T5; m191 regime).
// __launch_bounds__(512, 4) caps unified regs at 128 -> VGPR 64, 2 blocks/CU, 16 waves/CU.
// grid = 2050: bid < 2048 -> batch = bid>>1, chunk c = bid&1; bid >= 2048 -> doc chunk.
__global__ __launch_bounds__(512, 4)
void conv_body(const float* __restrict__ X, const bf16_t* __restrict__ Wswz,
               const float* __restrict__ bias, float* __restrict__ part,
               const float* __restrict__ X2, const bf16_t* __restrict__ W2,
               const float* __restrict__ bias2) {
    constexpr int NFRAG = 8;
    constexpr int TT    = 128;
    constexpr int NROWS = TT + 1;
    __shared__ bf16_t Xlds[NROWS * 300 + 8];
    __shared__ float  feat[256];

    const int tid = threadIdx.x;
    const int l   = tid & 63;
    const int w   = tid >> 6;
    const int g   = l >> 4;
    const int l15 = l & 15;

    const float* Xb;
    const bf16_t* Wb;
    const float* bp;
    int slot, t0;
    if ((int)blockIdx.x >= 2048) {               // doc rider
        int c = blockIdx.x - 2048;
        Xb = X2; Wb = W2; bp = bias2;
        slot = 2048 + c;
        t0 = c * TT;
    } else {
        int batch = blockIdx.x >> 1;
        int c = blockIdx.x & 1;
        Xb = X + (size_t)batch * 60000;
        Wb = Wswz; bp = bias;
        slot = batch * 2 + c;
        t0 = c * TT;
    }

    // ---- stage rows [t0, t0+NROWS) of X as bf16, 4 loads in flight per thread ----
    {
        const int vr  = (200 - t0 < NROWS) ? (200 - t0) : NROWS;
        const float4* s4 = (const float4*)(Xb + (size_t)t0 * 300);
        const int nF4 = vr * 75;
        for (int v0 = tid; v0 < nF4; v0 += 512 * 4) {
            float4 t[4];
#pragma unroll
            for (int q = 0; q < 4; ++q) {
                int v = v0 + q * 512;
                if (v < nF4) t[q] = s4[v];
            }
#pragma unroll
            for (int q = 0; q < 4; ++q) {
                int v = v0 + q * 512;
                if (v < nF4) {
                    bf16x4 hv = { (bf16_t)t[q].x, (bf16_t)t[q].y, (bf16_t)t[q].z, (bf16_t)t[q].w };
                    *(bf16x4*)(Xlds + v * 4) = hv;
                }
            }
        }
        bf16x4 z4 = { (bf16_t)0.f, (bf16_t)0.f, (bf16_t)0.f, (bf16_t)0.f };
        for (int v = nF4 + tid; v < NROWS * 75; v += 512)
            *(bf16x4*)(Xlds + v * 4) = z4;
        if (tid < 4) ((unsigned int*)(Xlds + NROWS * 300))[tid] = 0u;   // 16B guard (k->607 overrun)
    }

    // A-tile pointer: wave w's 2 f-tiles at K-step ks live at ((ks*16 + 2w + i)*512 + l*8)
    const bf16_t* wa = Wb + ((size_t)(2 * w) * 512 + (size_t)l * 8);

    int boff[NFRAG];
#pragma unroll
    for (int j = 0; j < NFRAG; j++)
        boff[j] = (j * 16 + l15) * 300 + g * 8;

    bf16x8 aCur[2], aNxt[2];
#pragma unroll
    for (int i = 0; i < 2; i++) aCur[i] = *(const bf16x8*)(wa + i * 512);

    __syncthreads();

    f32x4 acc[2][NFRAG];
#pragma unroll
    for (int i = 0; i < 2; i++)
#pragma unroll
        for (int j = 0; j < NFRAG; j++)
            acc[i][j] = (f32x4){0.f, 0.f, 0.f, 0.f};

    for (int ks = 0; ks < NKS; ++ks) {
        if (ks + 1 < NKS) {
            const bf16_t* wn_p = wa + (size_t)(ks + 1) * 16 * 512;
#pragma unroll
            for (int i = 0; i < 2; i++) aNxt[i] = *(const bf16x8*)(wn_p + i * 512);
        }
        const int k0 = ks * 32;
        bf16x8 bb[NFRAG];
#pragma unroll
        for (int j = 0; j < NFRAG; j++) {
            bf16x4 lo = *(const bf16x4*)(Xlds + boff[j] + k0);
            bf16x4 hi = *(const bf16x4*)(Xlds + boff[j] + k0 + 4);
            bb[j] = __builtin_shufflevector(lo, hi, 0, 1, 2, 3, 4, 5, 6, 7);
        }
        __builtin_amdgcn_s_setprio(1);
#pragma unroll
        for (int i = 0; i < 2; i++)
#pragma unroll
            for (int j = 0; j < NFRAG; j++)
                acc[i][j] = __builtin_amdgcn_mfma_f32_16x16x32_bf16(aCur[i], bb[j], acc[i][j], 0, 0, 0);
        __builtin_amdgcn_s_setprio(0);
#pragma unroll
        for (int i = 0; i < 2; i++) aCur[i] = aNxt[i];
    }

    // ---- epilogue: relu(C + bias), mask t<199, reduce over t; coalesced write via feat ----
#pragma unroll
    for (int i = 0; i < 2; i++) {
#pragma unroll
        for (int r = 0; r < 4; r++) {
            const int row = w * 32 + i * 16 + g * 4 + r;
            const float bi = bp[row];
            float s = 0.f;
#pragma unroll
            for (int j = 0; j < NFRAG; j++) {
                int t = t0 + j * 16 + l15;
                float v = acc[i][j][r] + bi;
                v = fmaxf(v, 0.f);
                s += (t < 199) ? v : 0.f;
            }
            s += __shfl_xor(s, 1);
            s += __shfl_xor(s, 2);
            s += __shfl_xor(s, 4);
            s += __shfl_xor(s, 8);
            if (l15 == 0) feat[row] = s;
        }
    }
    __syncthreads();
    if (tid < 256)
        part[(size_t)slot * 256 + tid] = feat[tid];
}

// ---------------- combine 2 partials + unit-normalize; nebT column-major, doc -> nmd ----------------
__global__ __launch_bounds__(256)
void combine_norm(const float* __restrict__ part, float* __restrict__ nebT,
                  float* __restrict__ nmd) {
    __shared__ float red[4];
    int bid = blockIdx.x, tid = threadIdx.x;
    float v = part[((size_t)bid * 2 + 0) * 256 + tid]
            + part[((size_t)bid * 2 + 1) * 256 + tid];
    float sq = v * v;
    sq += __shfl_xor(sq, 1);
    sq += __shfl_xor(sq, 2);
    sq += __shfl_xor(sq, 4);
    sq += __shfl_xor(sq, 8);
    sq += __shfl_xor(sq, 16);
    sq += __shfl_xor(sq, 32);
    if ((tid & 63) == 0) red[tid >> 6] = sq;
    __syncthreads();
    float tot = red[0] + red[1] + red[2] + red[3];
    float o = v / sqrtf(tot);
    if (bid >= 1024) nmd[tid] = o;
    else             nebT[(size_t)tid * 1024 + bid] = o;
}

// ---------------- small branches: 4 batches per block, all indices compile-time ----------------
template<int NF>
__device__ __forceinline__ void kloop_s(const bf16_t* __restrict__ wa,
        const bf16_t* __restrict__ buf, f32x4 (&acc)[2][NF], const int (&boff)[NF]) {
    bf16x8 aCur[2], aNxt[2];
    aCur[0] = *(const bf16x8*)(wa);
    aCur[1] = *(const bf16x8*)(wa + 512);
#pragma unroll
    for (int ks = 0; ks < NKS; ++ks) {
        if (ks + 1 < NKS) {
            const bf16_t* wn = wa + (size_t)(ks + 1) * (16 * 512);
            aNxt[0] = *(const bf16x8*)(wn);
            aNxt[1] = *(const bf16x8*)(wn + 512);
        }
        const int k0 = ks * 32;
#pragma unroll
        for (int j = 0; j < NF; ++j) {
            const bf16_t* p = buf + boff[j] + k0;
            bf16x4 lo = *(const bf16x4*)(p);
            bf16x4 hi = *(const bf16x4*)(p + 4);
            bf16x8 bb = __builtin_shufflevector(lo, hi, 0, 1, 2, 3, 4, 5, 6, 7);
            acc[0][j] = __builtin_amdgcn_mfma_f32_16x16x32_bf16(aCur[0], bb, acc[0][j], 0, 0, 0);
            acc[1][j] = __builtin_amdgcn_mfma_f32_16x16x32_bf16(aCur[1], bb, acc[1][j], 0, 0, 0);
        }
        aCur[0] = aNxt[0]; aCur[1] = aNxt[1];
    }
}

template<int NFB, int L, int T, int BSTR, int ARRE>
__global__ __launch_bounds__(512, 4)
void conv_small(const float* __restrict__ XA, const bf16_t* __restrict__ WA,
                const float* __restrict__ bA, float* __restrict__ outA,
                const float* __restrict__ XB, const bf16_t* __restrict__ WB,
                const float* __restrict__ bB, float* __restrict__ outB,
                int nABlocks) {
    constexpr int NTOT = 4 * NFB;
    __shared__ bf16_t Xs[ARRE];
    __shared__ float feat4[4][256];

    const int tid = threadIdx.x, l = tid & 63, w = tid >> 6, g = l >> 4, l15 = l & 15;
    const bool modeA = ((int)blockIdx.x < nABlocks);
    const int grp = modeA ? (int)blockIdx.x : ((int)blockIdx.x - nABlocks);
    const int batch0 = grp * 4;
    const float* Xsrc = modeA ? XA : XB;
    const bf16_t* Wb = modeA ? WA : WB;
    const float* bp = modeA ? bA : bB;

#pragma unroll
    for (int b = 0; b < 4; ++b) {
        const float4* s4 = (const float4*)(Xsrc + (size_t)(batch0 + b) * (L * 300));
        for (int v = tid; v < L * 75; v += 512) {
            float4 f = s4[v];
            bf16x4 h = { (bf16_t)f.x, (bf16_t)f.y, (bf16_t)f.z, (bf16_t)f.w };
            *(bf16x4*)(Xs + b * BSTR + v * 4) = h;
        }
        if (tid < 2) {
            bf16x4 z = { (bf16_t)0.f, (bf16_t)0.f, (bf16_t)0.f, (bf16_t)0.f };
            *(bf16x4*)(Xs + b * BSTR + L * 300 + tid * 4) = z;
        }
    }
    __syncthreads();

    int boff[NTOT];
#pragma unroll
    for (int j = 0; j < NTOT; ++j)
        boff[j] = (j / NFB) * BSTR + ((j % NFB) * 16 + l15) * 300 + g * 8;

    f32x4 acc[2][NTOT];
#pragma unroll
    for (int a = 0; a < 2; a++)
#pragma unroll
        for (int j = 0; j < NTOT; j++) acc[a][j] = (f32x4){0.f, 0.f, 0.f, 0.f};

    const bf16_t* wa = Wb + (size_t)(2 * w) * 512 + (size_t)l * 8;
    kloop_s<NTOT>(wa, Xs, acc, boff);

#pragma unroll
    for (int jb = 0; jb < 4; ++jb) {
#pragma unroll
        for (int a = 0; a < 2; a++)
#pragma unroll
            for (int r = 0; r < 4; r++) {
                const float bi = bp[32 * w + a * 16 + g * 4 + r];
                float s = 0.f;
#pragma unroll
                for (int jf = 0; jf < NFB; ++jf) {
                    int t = jf * 16 + l15;
                    float v = acc[a][jb * NFB + jf][r] + bi;
                    v = fmaxf(v, 0.f);
                    s += (t < T) ? v : 0.f;
                }
                s += __shfl_xor(s, 1);
                s += __shfl_xor(s, 2);
                s += __shfl_xor(s, 4);
                s += __shfl_xor(s, 8);
                if (l15 == 0) feat4[jb][32 * w + a * 16 + g * 4 + r] = s;
            }
    }
    __syncthreads();

    if (w < 4) {
        float vv[4];
        float sq = 0.f;
#pragma unroll
        for (int q = 0; q < 4; q++) { vv[q] = feat4[w][l * 4 + q]; sq += vv[q] * vv[q]; }
        sq += __shfl_xor(sq, 1);
        sq += __shfl_xor(sq, 2);
        sq += __shfl_xor(sq, 4);
        sq += __shfl_xor(sq, 8);
        sq += __shfl_xor(sq, 16);
        sq += __shfl_xor(sq, 32);
        float rsq = 1.f / sqrtf(sq);
        int batch = batch0 + w;
        if (modeA) {
#pragma unroll
            for (int q = 0; q < 4; q++)
                outA[(size_t)(l * 4 + q) * 1024 + batch] = vv[q] * rsq;
        } else {
            float4 o = { vv[0] * rsq, vv[1] * rsq, vv[2] * rsq, vv[3] * rsq };
            *(float4*)(outB + (size_t)batch * 256 + l * 4) = o;
        }
    }
}

// ---------------- pair pass 1: tile 4m x 256n per block (grid 256); dt/db FUSED inline ----------------
__global__ __launch_bounds__(256)
void pair1(const float* __restrict__ nms, const float* __restrict__ nmc,
           const float* __restrict__ netT, const float* __restrict__ nebT,
           const float* __restrict__ nmd,
           const float* __restrict__ wl, const float* __restrict__ bl,
           const int* __restrict__ me, float* __restrict__ out,
           float* __restrict__ epart) {
    __shared__ float sA[4 * 256], sB[4 * 256], md[256];
    const int tid = threadIdx.x;
    const int mt = blockIdx.x >> 2;
    const int nt = blockIdx.x & 3;
    const int m0 = mt * 4, n0 = nt * 256;
    for (int v = tid; v < 1024; v += 256) {
        sA[v] = nms[(size_t)m0 * 256 + v];
        sB[v] = nmc[(size_t)m0 * 256 + v];
    }
    md[tid] = nmd[tid];
    __syncthreads();
    const int ws = tid >> 6;
    const int nl = tid & 63;
    const int n  = n0 + nl * 4;
    const int m  = m0 + ws;

    float dst[4] = {0,0,0,0}, dct[4] = {0,0,0,0}, dsb[4] = {0,0,0,0}, dcb[4] = {0,0,0,0};
    float dtq[4] = {0,0,0,0}, dbq[4] = {0,0,0,0};
    for (int k = 0; k < 256; ++k) {
        float4 tv = *(const float4*)(netT + (size_t)k * 1024 + n);
        float4 bv = *(const float4*)(nebT + (size_t)k * 1024 + n);
        float a = sA[ws * 256 + k];
        float c = sB[ws * 256 + k];
        float mk = md[k];
        dst[0] += a * tv.x; dst[1] += a * tv.y; dst[2] += a * tv.z; dst[3] += a * tv.w;
        dct[0] += c * tv.x; dct[1] += c * tv.y; dct[2] += c * tv.z; dct[3] += c * tv.w;
        dsb[0] += a * bv.x; dsb[1] += a * bv.y; dsb[2] += a * bv.z; dsb[3] += a * bv.w;
        dcb[0] += c * bv.x; dcb[1] += c * bv.y; dcb[2] += c * bv.z; dcb[3] += c * bv.w;
        dtq[0] += mk * tv.x; dtq[1] += mk * tv.y; dtq[2] += mk * tv.z; dtq[3] += mk * tv.w;
        dbq[0] += mk * bv.x; dbq[1] += mk * bv.y; dbq[2] += mk * bv.z; dbq[3] += mk * bv.w;
    }

    float w0 = wl[0], w1 = wl[1], w2 = wl[2], w3 = wl[3], w4 = wl[4], w5 = wl[5], b = bl[0];
    const int* mp = me + (size_t)m * 1024 + n;
    float scv[4], evv[4];
    float esum = 0.f;
#pragma unroll
    for (int q = 0; q < 4; q++) {
        float msk = (float)mp[q];
        float f_st = dst[q] * 0.5f + 0.5f;
        float f_dt = dtq[q] * 0.5f + 0.5f;
        float f_ct = dct[q] * 0.5f + 0.5f;
        float f_sb = dsb[q] * 0.5f + 0.5f;
        float f_db = dbq[q] * 0.5f + 0.5f;
        float f_cb = dcb[q] * 0.5f + 0.5f;
        float s = f_st * w0 + f_dt * w1 + f_ct * w2 + f_sb * w3 + f_db * w4 + f_cb * w5 + b;
        s = (msk != 0.f) ? s : 0.f;
        scv[q] = s;
        evv[q] = (msk != 0.f) ? expf(s / 0.1f) : 0.f;
        esum += evv[q];
    }
    esum += __shfl_xor(esum, 1);
    esum += __shfl_xor(esum, 2);
    esum += __shfl_xor(esum, 4);
    esum += __shfl_xor(esum, 8);
    esum += __shfl_xor(esum, 16);
    esum += __shfl_xor(esum, 32);
    if (nl == 0) epart[(size_t)m * 4 + nt] = esum;

    *(float4*)(out + (size_t)m * 1024 + n) = *(float4*)scv;
    *(float4*)(out + 262144 + (size_t)m * 1024 + n) = *(float4*)evv;
}

// ---------------- pair pass 2: row-normalize e in place ----------------
__global__ __launch_bounds__(256)
void pair2(const float* __restrict__ epart, float* __restrict__ out2) {
    int m = blockIdx.x, tid = threadIdx.x;
    float tot = epart[(size_t)m * 4 + 0] + epart[(size_t)m * 4 + 1]
              + epart[(size_t)m * 4 + 2] + epart[(size_t)m * 4 + 3];
    float inv = 1.f / tot;
#pragma unroll
    for (int q = 0; q < 4; q++)
        out2[(size_t)m * 1024 + q * 256 + tid] *= inv;
}

extern "C" void kernel_launch(void* const* d_in, const int* in_sizes, int n_in,
                              void* d_out, int out_size, void* d_ws, size_t ws_size,
                              hipStream_t stream) {
    const float* mention = (const float*)d_in[0];
    const float* context = (const float*)d_in[1];
    const float* doc     = (const float*)d_in[2];
    const float* title   = (const float*)d_in[3];
    const float* body    = (const float*)d_in[4];
    const float* W_ms = (const float*)d_in[5];  const float* b_ms = (const float*)d_in[6];
    const float* W_mc = (const float*)d_in[7];  const float* b_mc = (const float*)d_in[8];
    const float* W_md = (const float*)d_in[9];  const float* b_md = (const float*)d_in[10];
    const float* W_et = (const float*)d_in[11]; const float* b_et = (const float*)d_in[12];
    const float* W_eb = (const float*)d_in[13]; const float* b_eb = (const float*)d_in[14];
    const float* w_local = (const float*)d_in[15];
    const float* b_local = (const float*)d_in[16];
    const int*   me      = (const int*)d_in[17];
    float* out = (float*)d_out;

    char* ws = (char*)d_ws;
    bf16_t* Wp = (bf16_t*)ws;
    size_t off = (size_t)5 * FNUM * KPAD * 2;             // swizzled W: 1,556,480 B
    float* part = (float*)(ws + off); off += (size_t)1025 * 2 * 256 * 4;
    float* nms  = (float*)(ws + off); off += 256 * 256 * 4;
    float* nmc  = (float*)(ws + off); off += 256 * 256 * 4;
    float* netT = (float*)(ws + off); off += 1024 * 256 * 4;
    float* nebT = (float*)(ws + off); off += 1024 * 256 * 4;
    float* nmd  = (float*)(ws + off); off += 256 * 4;
    float* epart= (float*)(ws + off); off += 256 * 4 * 4;

    const bf16_t* Wms = Wp + (size_t)0 * FNUM * KPAD;
    const bf16_t* Wmc = Wp + (size_t)1 * FNUM * KPAD;
    const bf16_t* Wmd = Wp + (size_t)2 * FNUM * KPAD;
    const bf16_t* Wet = Wp + (size_t)3 * FNUM * KPAD;
    const bf16_t* Web = Wp + (size_t)4 * FNUM * KPAD;

    prep_w_swz<<<380, 256, 0, stream>>>(W_ms, W_mc, W_md, W_et, W_eb, Wp);

    // body: single-chunk-per-block tiles, 8M x 1N wave mapping (grid 2050)
    conv_body<<<2050, 512, 0, stream>>>(body, Web, b_eb, part, doc, Wmd, b_md);

    conv_small<2, 20, 19, 6016, 27968><<<320, 512, 0, stream>>>(
        title, Wet, b_et, netT, context, Wmc, b_mc, nmc, 256);
    conv_small<1, 10, 9, 5120, 20480><<<64, 512, 0, stream>>>(
        mention, Wms, b_ms, netT, mention, Wms, b_ms, nms, 0);

    combine_norm<<<1025, 256, 0, stream>>>(part, nebT, nmd);
    pair1<<<256, 256, 0, stream>>>(nms, nmc, netT, nebT, nmd, w_local, b_local, me, out, epart);
    pair2<<<256, 256, 0, stream>>>(epart, out + 262144);
}

// Round 22
// 209.808 us; speedup vs baseline: 1.2258x; 1.0385x over previous
//
#include <hip/hip_runtime.h>
#include <math.h>

typedef __bf16 bf16_t;
typedef __bf16 bf16x4 __attribute__((ext_vector_type(4)));
typedef __bf16 bf16x8 __attribute__((ext_vector_type(8)));
typedef float  f32x4  __attribute__((ext_vector_type(4)));

#define FNUM 256
#define KPAD 608            // 600 padded to 608 (19 K-steps of 32)
#define NKS  19

// ---------------- W prep: f32 [256][600] -> swizzled bf16 MFMA-fragment tiles ----------------
// Tile (ks, ft): 64 lanes x 8 bf16 contiguous. lane l -> f = ft*16+(l&15), k = ks*32+(l>>4)*8+e.
__global__ __launch_bounds__(256)
void prep_w_swz(const float* __restrict__ w0, const float* __restrict__ w1,
                const float* __restrict__ w2, const float* __restrict__ w3,
                const float* __restrict__ w4, bf16_t* __restrict__ wp) {
    int tg = blockIdx.x * 4 + (threadIdx.x >> 6);    // 5*19*16 = 1520 tiles
    if (tg >= 1520) return;
    int l  = threadIdx.x & 63;
    int br = tg / 304;
    int rem = tg % 304;
    int ks = rem / 16, ft = rem % 16;
    const float* src;
    switch (br) {
        case 0: src = w0; break;
        case 1: src = w1; break;
        case 2: src = w2; break;
        case 3: src = w3; break;
        default: src = w4; break;
    }
    int f = ft * 16 + (l & 15);
    int k0 = ks * 32 + (l >> 4) * 8;
    bf16x8 v;
#pragma unroll
    for (int e = 0; e < 8; e++) {
        int k = k0 + e;
        v[e] = (k < 600) ? (bf16_t)src[(size_t)f * 600 + k] : (bf16_t)0.f;
    }
    *(bf16x8*)(wp + (size_t)br * FNUM * KPAD + ((size_t)(ks * 16 + ft) * 512 + (size_t)l * 8)) = v;
}

// ---------------- body conv tile: ONE 256f x 128t chunk per block, 8M x 1N waves ----------------
// 512 threads = 8 waves; wave w owns f [w*32, w*32+32) (2 m-frags) x ALL 128 t (8 n-frags)
// -> 16 MFMA/step/wave, 2 W-tile loads/step, no L1 duplication. Batched stage (4 float4 in
// flight). s_setprio(1) brackets the MFMA cluster: with 2 independent blocks/CU, MFMA waves
// of one block win issue arbitration over the other block's staging waves (T5 confirmed:
// R19 163us -> R21 140us, MfmaUtil 20.5 -> 24.3%).
// __launch_bounds__(512, 4) caps unified regs at 128 -> VGPR 64, 2 blocks/CU, 16 waves/CU.
// grid = 2050: bid < 2048 -> batch = bid>>1, chunk c = bid&1; bid >= 2048 -> doc chunk.
__global__ __launch_bounds__(512, 4)
void conv_body(const float* __restrict__ X, const bf16_t* __restrict__ Wswz,
               const float* __restrict__ bias, float* __restrict__ part,
               const float* __restrict__ X2, const bf16_t* __restrict__ W2,
               const float* __restrict__ bias2) {
    constexpr int NFRAG = 8;
    constexpr int TT    = 128;
    constexpr int NROWS = TT + 1;
    __shared__ bf16_t Xlds[NROWS * 300 + 8];
    __shared__ float  feat[256];

    const int tid = threadIdx.x;
    const int l   = tid & 63;
    const int w   = tid >> 6;
    const int g   = l >> 4;
    const int l15 = l & 15;

    const float* Xb;
    const bf16_t* Wb;
    const float* bp;
    int slot, t0;
    if ((int)blockIdx.x >= 2048) {               // doc rider
        int c = blockIdx.x - 2048;
        Xb = X2; Wb = W2; bp = bias2;
        slot = 2048 + c;
        t0 = c * TT;
    } else {
        int batch = blockIdx.x >> 1;
        int c = blockIdx.x & 1;
        Xb = X + (size_t)batch * 60000;
        Wb = Wswz; bp = bias;
        slot = batch * 2 + c;
        t0 = c * TT;
    }

    // ---- stage rows [t0, t0+NROWS) of X as bf16, 4 loads in flight per thread ----
    {
        const int vr  = (200 - t0 < NROWS) ? (200 - t0) : NROWS;
        const float4* s4 = (const float4*)(Xb + (size_t)t0 * 300);
        const int nF4 = vr * 75;
        for (int v0 = tid; v0 < nF4; v0 += 512 * 4) {
            float4 t[4];
#pragma unroll
            for (int q = 0; q < 4; ++q) {
                int v = v0 + q * 512;
                if (v < nF4) t[q] = s4[v];
            }
#pragma unroll
            for (int q = 0; q < 4; ++q) {
                int v = v0 + q * 512;
                if (v < nF4) {
                    bf16x4 hv = { (bf16_t)t[q].x, (bf16_t)t[q].y, (bf16_t)t[q].z, (bf16_t)t[q].w };
                    *(bf16x4*)(Xlds + v * 4) = hv;
                }
            }
        }
        bf16x4 z4 = { (bf16_t)0.f, (bf16_t)0.f, (bf16_t)0.f, (bf16_t)0.f };
        for (int v = nF4 + tid; v < NROWS * 75; v += 512)
            *(bf16x4*)(Xlds + v * 4) = z4;
        if (tid < 4) ((unsigned int*)(Xlds + NROWS * 300))[tid] = 0u;   // 16B guard (k->607 overrun)
    }

    // A-tile pointer: wave w's 2 f-tiles at K-step ks live at ((ks*16 + 2w + i)*512 + l*8)
    const bf16_t* wa = Wb + ((size_t)(2 * w) * 512 + (size_t)l * 8);

    int boff[NFRAG];
#pragma unroll
    for (int j = 0; j < NFRAG; j++)
        boff[j] = (j * 16 + l15) * 300 + g * 8;

    bf16x8 aCur[2], aNxt[2];
#pragma unroll
    for (int i = 0; i < 2; i++) aCur[i] = *(const bf16x8*)(wa + i * 512);

    __syncthreads();

    f32x4 acc[2][NFRAG];
#pragma unroll
    for (int i = 0; i < 2; i++)
#pragma unroll
        for (int j = 0; j < NFRAG; j++)
            acc[i][j] = (f32x4){0.f, 0.f, 0.f, 0.f};

    for (int ks = 0; ks < NKS; ++ks) {
        if (ks + 1 < NKS) {
            const bf16_t* wn_p = wa + (size_t)(ks + 1) * 16 * 512;
#pragma unroll
            for (int i = 0; i < 2; i++) aNxt[i] = *(const bf16x8*)(wn_p + i * 512);
        }
        const int k0 = ks * 32;
        bf16x8 bb[NFRAG];
#pragma unroll
        for (int j = 0; j < NFRAG; j++) {
            bf16x4 lo = *(const bf16x4*)(Xlds + boff[j] + k0);
            bf16x4 hi = *(const bf16x4*)(Xlds + boff[j] + k0 + 4);
            bb[j] = __builtin_shufflevector(lo, hi, 0, 1, 2, 3, 4, 5, 6, 7);
        }
        __builtin_amdgcn_s_setprio(1);
#pragma unroll
        for (int i = 0; i < 2; i++)
#pragma unroll
            for (int j = 0; j < NFRAG; j++)
                acc[i][j] = __builtin_amdgcn_mfma_f32_16x16x32_bf16(aCur[i], bb[j], acc[i][j], 0, 0, 0);
        __builtin_amdgcn_s_setprio(0);
#pragma unroll
        for (int i = 0; i < 2; i++) aCur[i] = aNxt[i];
    }

    // ---- epilogue: relu(C + bias), mask t<199, reduce over t; coalesced write via feat ----
#pragma unroll
    for (int i = 0; i < 2; i++) {
#pragma unroll
        for (int r = 0; r < 4; r++) {
            const int row = w * 32 + i * 16 + g * 4 + r;
            const float bi = bp[row];
            float s = 0.f;
#pragma unroll
            for (int j = 0; j < NFRAG; j++) {
                int t = t0 + j * 16 + l15;
                float v = acc[i][j][r] + bi;
                v = fmaxf(v, 0.f);
                s += (t < 199) ? v : 0.f;
            }
            s += __shfl_xor(s, 1);
            s += __shfl_xor(s, 2);
            s += __shfl_xor(s, 4);
            s += __shfl_xor(s, 8);
            if (l15 == 0) feat[row] = s;
        }
    }
    __syncthreads();
    if (tid < 256)
        part[(size_t)slot * 256 + tid] = feat[tid];
}

// ---------------- combine 2 partials + unit-normalize; nebT column-major, doc -> nmd ----------------
__global__ __launch_bounds__(256)
void combine_norm(const float* __restrict__ part, float* __restrict__ nebT,
                  float* __restrict__ nmd) {
    __shared__ float red[4];
    int bid = blockIdx.x, tid = threadIdx.x;
    float v = part[((size_t)bid * 2 + 0) * 256 + tid]
            + part[((size_t)bid * 2 + 1) * 256 + tid];
    float sq = v * v;
    sq += __shfl_xor(sq, 1);
    sq += __shfl_xor(sq, 2);
    sq += __shfl_xor(sq, 4);
    sq += __shfl_xor(sq, 8);
    sq += __shfl_xor(sq, 16);
    sq += __shfl_xor(sq, 32);
    if ((tid & 63) == 0) red[tid >> 6] = sq;
    __syncthreads();
    float tot = red[0] + red[1] + red[2] + red[3];
    float o = v / sqrtf(tot);
    if (bid >= 1024) nmd[tid] = o;
    else             nebT[(size_t)tid * 1024 + bid] = o;
}

// ---------------- small branches: 4 batches per block, all indices compile-time ----------------
// setprio bracket on the MFMA pair (same T5 mechanism as conv_body: multiple independent
// blocks/CU, each alternating serial-stage and MFMA phases).
template<int NF>
__device__ __forceinline__ void kloop_s(const bf16_t* __restrict__ wa,
        const bf16_t* __restrict__ buf, f32x4 (&acc)[2][NF], const int (&boff)[NF]) {
    bf16x8 aCur[2], aNxt[2];
    aCur[0] = *(const bf16x8*)(wa);
    aCur[1] = *(const bf16x8*)(wa + 512);
#pragma unroll
    for (int ks = 0; ks < NKS; ++ks) {
        if (ks + 1 < NKS) {
            const bf16_t* wn = wa + (size_t)(ks + 1) * (16 * 512);
            aNxt[0] = *(const bf16x8*)(wn);
            aNxt[1] = *(const bf16x8*)(wn + 512);
        }
        const int k0 = ks * 32;
        __builtin_amdgcn_s_setprio(1);
#pragma unroll
        for (int j = 0; j < NF; ++j) {
            const bf16_t* p = buf + boff[j] + k0;
            bf16x4 lo = *(const bf16x4*)(p);
            bf16x4 hi = *(const bf16x4*)(p + 4);
            bf16x8 bb = __builtin_shufflevector(lo, hi, 0, 1, 2, 3, 4, 5, 6, 7);
            acc[0][j] = __builtin_amdgcn_mfma_f32_16x16x32_bf16(aCur[0], bb, acc[0][j], 0, 0, 0);
            acc[1][j] = __builtin_amdgcn_mfma_f32_16x16x32_bf16(aCur[1], bb, acc[1][j], 0, 0, 0);
        }
        __builtin_amdgcn_s_setprio(0);
        aCur[0] = aNxt[0]; aCur[1] = aNxt[1];
    }
}

template<int NFB, int L, int T, int BSTR, int ARRE>
__global__ __launch_bounds__(512, 4)
void conv_small(const float* __restrict__ XA, const bf16_t* __restrict__ WA,
                const float* __restrict__ bA, float* __restrict__ outA,
                const float* __restrict__ XB, const bf16_t* __restrict__ WB,
                const float* __restrict__ bB, float* __restrict__ outB,
                int nABlocks) {
    constexpr int NTOT = 4 * NFB;
    __shared__ bf16_t Xs[ARRE];
    __shared__ float feat4[4][256];

    const int tid = threadIdx.x, l = tid & 63, w = tid >> 6, g = l >> 4, l15 = l & 15;
    const bool modeA = ((int)blockIdx.x < nABlocks);
    const int grp = modeA ? (int)blockIdx.x : ((int)blockIdx.x - nABlocks);
    const int batch0 = grp * 4;
    const float* Xsrc = modeA ? XA : XB;
    const bf16_t* Wb = modeA ? WA : WB;
    const float* bp = modeA ? bA : bB;

#pragma unroll
    for (int b = 0; b < 4; ++b) {
        const float4* s4 = (const float4*)(Xsrc + (size_t)(batch0 + b) * (L * 300));
        for (int v = tid; v < L * 75; v += 512) {
            float4 f = s4[v];
            bf16x4 h = { (bf16_t)f.x, (bf16_t)f.y, (bf16_t)f.z, (bf16_t)f.w };
            *(bf16x4*)(Xs + b * BSTR + v * 4) = h;
        }
        if (tid < 2) {
            bf16x4 z = { (bf16_t)0.f, (bf16_t)0.f, (bf16_t)0.f, (bf16_t)0.f };
            *(bf16x4*)(Xs + b * BSTR + L * 300 + tid * 4) = z;
        }
    }
    __syncthreads();

    int boff[NTOT];
#pragma unroll
    for (int j = 0; j < NTOT; ++j)
        boff[j] = (j / NFB) * BSTR + ((j % NFB) * 16 + l15) * 300 + g * 8;

    f32x4 acc[2][NTOT];
#pragma unroll
    for (int a = 0; a < 2; a++)
#pragma unroll
        for (int j = 0; j < NTOT; j++) acc[a][j] = (f32x4){0.f, 0.f, 0.f, 0.f};

    const bf16_t* wa = Wb + (size_t)(2 * w) * 512 + (size_t)l * 8;
    kloop_s<NTOT>(wa, Xs, acc, boff);

#pragma unroll
    for (int jb = 0; jb < 4; ++jb) {
#pragma unroll
        for (int a = 0; a < 2; a++)
#pragma unroll
            for (int r = 0; r < 4; r++) {
                const float bi = bp[32 * w + a * 16 + g * 4 + r];
                float s = 0.f;
#pragma unroll
                for (int jf = 0; jf < NFB; ++jf) {
                    int t = jf * 16 + l15;
                    float v = acc[a][jb * NFB + jf][r] + bi;
                    v = fmaxf(v, 0.f);
                    s += (t < T) ? v : 0.f;
                }
                s += __shfl_xor(s, 1);
                s += __shfl_xor(s, 2);
                s += __shfl_xor(s, 4);
                s += __shfl_xor(s, 8);
                if (l15 == 0) feat4[jb][32 * w + a * 16 + g * 4 + r] = s;
            }
    }
    __syncthreads();

    if (w < 4) {
        float vv[4];
        float sq = 0.f;
#pragma unroll
        for (int q = 0; q < 4; q++) { vv[q] = feat4[w][l * 4 + q]; sq += vv[q] * vv[q]; }
        sq += __shfl_xor(sq, 1);
        sq += __shfl_xor(sq, 2);
        sq += __shfl_xor(sq, 4);
        sq += __shfl_xor(sq, 8);
        sq += __shfl_xor(sq, 16);
        sq += __shfl_xor(sq, 32);
        float rsq = 1.f / sqrtf(sq);
        int batch = batch0 + w;
        if (modeA) {
#pragma unroll
            for (int q = 0; q < 4; q++)
                outA[(size_t)(l * 4 + q) * 1024 + batch] = vv[q] * rsq;
        } else {
            float4 o = { vv[0] * rsq, vv[1] * rsq, vv[2] * rsq, vv[3] * rsq };
            *(float4*)(outB + (size_t)batch * 256 + l * 4) = o;
        }
    }
}

// ---------------- pair pass 1: tile 4m x 256n per block (grid 256); dt/db FUSED inline ----------------
__global__ __launch_bounds__(256)
void pair1(const float* __restrict__ nms, const float* __restrict__ nmc,
           const float* __restrict__ netT, const float* __restrict__ nebT,
           const float* __restrict__ nmd,
           const float* __restrict__ wl, const float* __restrict__ bl,
           const int* __restrict__ me, float* __restrict__ out,
           float* __restrict__ epart) {
    __shared__ float sA[4 * 256], sB[4 * 256], md[256];
    const int tid = threadIdx.x;
    const int mt = blockIdx.x >> 2;
    const int nt = blockIdx.x & 3;
    const int m0 = mt * 4, n0 = nt * 256;
    for (int v = tid; v < 1024; v += 256) {
        sA[v] = nms[(size_t)m0 * 256 + v];
        sB[v] = nmc[(size_t)m0 * 256 + v];
    }
    md[tid] = nmd[tid];
    __syncthreads();
    const int ws = tid >> 6;
    const int nl = tid & 63;
    const int n  = n0 + nl * 4;
    const int m  = m0 + ws;

    float dst[4] = {0,0,0,0}, dct[4] = {0,0,0,0}, dsb[4] = {0,0,0,0}, dcb[4] = {0,0,0,0};
    float dtq[4] = {0,0,0,0}, dbq[4] = {0,0,0,0};
    for (int k = 0; k < 256; ++k) {
        float4 tv = *(const float4*)(netT + (size_t)k * 1024 + n);
        float4 bv = *(const float4*)(nebT + (size_t)k * 1024 + n);
        float a = sA[ws * 256 + k];
        float c = sB[ws * 256 + k];
        float mk = md[k];
        dst[0] += a * tv.x; dst[1] += a * tv.y; dst[2] += a * tv.z; dst[3] += a * tv.w;
        dct[0] += c * tv.x; dct[1] += c * tv.y; dct[2] += c * tv.z; dct[3] += c * tv.w;
        dsb[0] += a * bv.x; dsb[1] += a * bv.y; dsb[2] += a * bv.z; dsb[3] += a * bv.w;
        dcb[0] += c * bv.x; dcb[1] += c * bv.y; dcb[2] += c * bv.z; dcb[3] += c * bv.w;
        dtq[0] += mk * tv.x; dtq[1] += mk * tv.y; dtq[2] += mk * tv.z; dtq[3] += mk * tv.w;
        dbq[0] += mk * bv.x; dbq[1] += mk * bv.y; dbq[2] += mk * bv.z; dbq[3] += mk * bv.w;
    }

    float w0 = wl[0], w1 = wl[1], w2 = wl[2], w3 = wl[3], w4 = wl[4], w5 = wl[5], b = bl[0];
    const int* mp = me + (size_t)m * 1024 + n;
    float scv[4], evv[4];
    float esum = 0.f;
#pragma unroll
    for (int q = 0; q < 4; q++) {
        float msk = (float)mp[q];
        float f_st = dst[q] * 0.5f + 0.5f;
        float f_dt = dtq[q] * 0.5f + 0.5f;
        float f_ct = dct[q] * 0.5f + 0.5f;
        float f_sb = dsb[q] * 0.5f + 0.5f;
        float f_db = dbq[q] * 0.5f + 0.5f;
        float f_cb = dcb[q] * 0.5f + 0.5f;
        float s = f_st * w0 + f_dt * w1 + f_ct * w2 + f_sb * w3 + f_db * w4 + f_cb * w5 + b;
        s = (msk != 0.f) ? s : 0.f;
        scv[q] = s;
        evv[q] = (msk != 0.f) ? expf(s / 0.1f) : 0.f;
        esum += evv[q];
    }
    esum += __shfl_xor(esum, 1);
    esum += __shfl_xor(esum, 2);
    esum += __shfl_xor(esum, 4);
    esum += __shfl_xor(esum, 8);
    esum += __shfl_xor(esum, 16);
    esum += __shfl_xor(esum, 32);
    if (nl == 0) epart[(size_t)m * 4 + nt] = esum;

    *(float4*)(out + (size_t)m * 1024 + n) = *(float4*)scv;
    *(float4*)(out + 262144 + (size_t)m * 1024 + n) = *(float4*)evv;
}

// ---------------- pair pass 2: row-normalize e in place ----------------
__global__ __launch_bounds__(256)
void pair2(const float* __restrict__ epart, float* __restrict__ out2) {
    int m = blockIdx.x, tid = threadIdx.x;
    float tot = epart[(size_t)m * 4 + 0] + epart[(size_t)m * 4 + 1]
              + epart[(size_t)m * 4 + 2] + epart[(size_t)m * 4 + 3];
    float inv = 1.f / tot;
#pragma unroll
    for (int q = 0; q < 4; q++)
        out2[(size_t)m * 1024 + q * 256 + tid] *= inv;
}

extern "C" void kernel_launch(void* const* d_in, const int* in_sizes, int n_in,
                              void* d_out, int out_size, void* d_ws, size_t ws_size,
                              hipStream_t stream) {
    const float* mention = (const float*)d_in[0];
    const float* context = (const float*)d_in[1];
    const float* doc     = (const float*)d_in[2];
    const float* title   = (const float*)d_in[3];
    const float* body    = (const float*)d_in[4];
    const float* W_ms = (const float*)d_in[5];  const float* b_ms = (const float*)d_in[6];
    const float* W_mc = (const float*)d_in[7];  const float* b_mc = (const float*)d_in[8];
    const float* W_md = (const float*)d_in[9];  const float* b_md = (const float*)d_in[10];
    const float* W_et = (const float*)d_in[11]; const float* b_et = (const float*)d_in[12];
    const float* W_eb = (const float*)d_in[13]; const float* b_eb = (const float*)d_in[14];
    const float* w_local = (const float*)d_in[15];
    const float* b_local = (const float*)d_in[16];
    const int*   me      = (const int*)d_in[17];
    float* out = (float*)d_out;

    char* ws = (char*)d_ws;
    bf16_t* Wp = (bf16_t*)ws;
    size_t off = (size_t)5 * FNUM * KPAD * 2;             // swizzled W: 1,556,480 B
    float* part = (float*)(ws + off); off += (size_t)1025 * 2 * 256 * 4;
    float* nms  = (float*)(ws + off); off += 256 * 256 * 4;
    float* nmc  = (float*)(ws + off); off += 256 * 256 * 4;
    float* netT = (float*)(ws + off); off += 1024 * 256 * 4;
    float* nebT = (float*)(ws + off); off += 1024 * 256 * 4;
    float* nmd  = (float*)(ws + off); off += 256 * 4;
    float* epart= (float*)(ws + off); off += 256 * 4 * 4;

    const bf16_t* Wms = Wp + (size_t)0 * FNUM * KPAD;
    const bf16_t* Wmc = Wp + (size_t)1 * FNUM * KPAD;
    const bf16_t* Wmd = Wp + (size_t)2 * FNUM * KPAD;
    const bf16_t* Wet = Wp + (size_t)3 * FNUM * KPAD;
    const bf16_t* Web = Wp + (size_t)4 * FNUM * KPAD;

    prep_w_swz<<<380, 256, 0, stream>>>(W_ms, W_mc, W_md, W_et, W_eb, Wp);

    // body: single-chunk-per-block tiles, 8M x 1N wave mapping (grid 2050)
    conv_body<<<2050, 512, 0, stream>>>(body, Web, b_eb, part, doc, Wmd, b_md);

    conv_small<2, 20, 19, 6016, 27968><<<320, 512, 0, stream>>>(
        title, Wet, b_et, netT, context, Wmc, b_mc, nmc, 256);
    conv_small<1, 10, 9, 5120, 20480><<<64, 512, 0, stream>>>(
        mention, Wms, b_ms, netT, mention, Wms, b_ms, nms, 0);

    combine_norm<<<1025, 256, 0, stream>>>(part, nebT, nmd);
    pair1<<<256, 256, 0, stream>>>(nms, nmc, netT, nebT, nmd, w_local, b_local, me, out, epart);
    pair2<<<256, 256, 0, stream>>>(epart, out + 262144);
}